// Round 8
// baseline (516.680 us; speedup 1.0000x reference)
//
#include <hip/hip_runtime.h>
#include <float.h>
#include <limits.h>
#include <math.h>

// ClusterLayer: B=131072 rows, K=1024 clusters, D=128.
// out (float32): [0] inertia/B, [1] xe/K, [2..2+B) cl as float.
//
// R8: 1-pass RNE-bf16 MFMA with R4's lean tracker (top-2 values + top-1 idx),
// R7 sync shape (8 x 32KB phases, counted vmcnt(4) double buffer). Flagged
// near-ties (gap < TAU) -> refine2: f32 full rescan -> top-2 -> exact f64.
//
// ws layout (bytes):
//   0      : double inertia_acc
//   8      : int    flag_cnt
//   16     : float  w2[1024]
//   4608   : short  wh[131072]     (256 KB, bf16-RNE W, tile fragment order)
//   266752 : int    flag_rows[16384]  -> end 332288

#define TAU 0.012f

using bf16x8 = __attribute__((ext_vector_type(8))) short;
using f32x4  = __attribute__((ext_vector_type(4))) float;
using s16x4  = __attribute__((ext_vector_type(4))) short;

static __device__ __forceinline__ short f2bf_rne(float f) {
    unsigned u = __float_as_uint(f);
    return (short)((u + 0x7FFFu + ((u >> 16) & 1u)) >> 16);
}
static __device__ __forceinline__ short f2bf_trunc(float f) {
    return (short)(__float_as_uint(f) >> 16);
}
static __device__ __forceinline__ float bf2f(short h) {
    return __uint_as_float(((unsigned int)(unsigned short)h) << 16);
}
static __device__ __forceinline__ bool lexlt(float v1, int i1, float v2, int i2) {
    return v1 < v2 || (v1 == v2 && i1 < i2);
}
static __device__ __forceinline__ void gload_lds16(const void* g, void* l) {
    __builtin_amdgcn_global_load_lds(
        (const __attribute__((address_space(1))) unsigned int*)g,
        (__attribute__((address_space(3))) unsigned int*)l, 16, 0, 0);
}
#define FENCE() do { asm volatile("" ::: "memory"); __builtin_amdgcn_sched_barrier(0); } while (0)

// W prep: w2 per cluster (f32-exact) + bf16-RNE hi image in 64-col-tile
// fragment order (proven R5-R7): shorts:
//   tile*8192 + (c>>4)*2048 + (d>>5)*512 + ((d>>3)&3)*128 + (c&15)*8 + (d&7)
__global__ void wprep_kernel(const float* __restrict__ W, float* __restrict__ w2,
                             short* __restrict__ wh, int write_wh)
{
    const int k = blockIdx.x;
    const int d = threadIdx.x;     // 0..127
    float v = W[(size_t)k * 128 + d];
    float sq = v * v;
    for (int off = 1; off < 64; off <<= 1) sq += __shfl_xor(sq, off, 64);
    __shared__ float p[2];
    if ((d & 63) == 0) p[d >> 6] = sq;
    __syncthreads();
    if (d == 0) w2[k] = p[0] + p[1];
    if (write_wh) {
        const int tile = k >> 6, c = k & 63;
        size_t base = (size_t)tile * 8192 + (size_t)(c >> 4) * 2048 + (size_t)(d >> 5) * 512
                    + (size_t)((d >> 3) & 3) * 128 + (size_t)(c & 15) * 8 + (size_t)(d & 7);
        wh[base] = f2bf_rne(v);
    }
}

// LDS (bytes): lB0 0..32768 | lB1 32768..65536 | lw2 65536..69632 |
//              lx2 69632..70144 | mscr 70144..72192 (128 x 4 ints) |
//              dred 72192..72320
__global__ __launch_bounds__(512, 4)
void dist_argmin_1p(const float* __restrict__ X, const short* __restrict__ wh,
                    const float* __restrict__ w2g, float* __restrict__ cl_out,
                    double* __restrict__ inertia_acc,
                    int* __restrict__ flag_cnt, int* __restrict__ flag_rows,
                    int flag_cap)
{
    __shared__ __align__(16) char smem[72320];
    char*   lB0  = smem;
    char*   lB1  = smem + 32768;
    float*  lw2  = (float*)(smem + 65536);
    float*  lx2  = (float*)(smem + 69632);
    int*    mscr = (int*)(smem + 70144);
    double* dred = (double*)(smem + 72192);

    const int tid    = threadIdx.x;
    const int lane   = tid & 63;
    const int laneLo = lane & 15;
    const int laneHi = lane >> 4;
    const int wid    = tid >> 6;
    const int rowg   = wid >> 1;
    const int colg   = wid & 1;
    const int rowbase = blockIdx.x * 128;

    // w2 -> LDS (K-loop must have zero global loads so vmcnt counting holds)
    lw2[tid]       = w2g[tid];
    lw2[tid + 512] = w2g[tid + 512];

    // ---- A (hi only, RNE) straight from global into registers + ||x||^2 ----
    bf16x8 ah[2][4];
    #pragma unroll
    for (int m = 0; m < 2; ++m) {
        const float* xp = X + (size_t)(rowbase + rowg * 32 + m * 16 + laneLo) * 128 + laneHi * 8;
        float s = 0.f;
        #pragma unroll
        for (int k0b = 0; k0b < 4; ++k0b) {
            float4 v0 = *reinterpret_cast<const float4*>(xp + k0b * 32);
            float4 v1 = *reinterpret_cast<const float4*>(xp + k0b * 32 + 4);
            float fv[8] = {v0.x, v0.y, v0.z, v0.w, v1.x, v1.y, v1.z, v1.w};
            bf16x8 hv;
            #pragma unroll
            for (int u = 0; u < 8; ++u) {
                s = fmaf(fv[u], fv[u], s);
                hv[u] = f2bf_rne(fv[u]);
            }
            ah[m][k0b] = hv;
        }
        s += __shfl_xor(s, 16, 64);     // combine 4 laneHi dim-slices
        s += __shfl_xor(s, 32, 64);
        if (colg == 0 && laneHi == 0) lx2[rowg * 32 + m * 16 + laneLo] = s;
    }

    // ---- issue phase 0 DMA -> lB0 (32 KB = 128 clusters; 4 x 16B/thread) ----
    #pragma unroll
    for (int q = 0; q < 4; ++q)
        gload_lds16((const char*)wh + wid * 4096 + q * 1024 + lane * 16,
                    lB0 + wid * 4096 + q * 1024);

    // drain my lw2/lx2 ds_writes before the first in-loop barrier
    asm volatile("s_waitcnt lgkmcnt(0)" ::: "memory");
    __builtin_amdgcn_sched_barrier(0);

    float t1v[2][4], t2v[2][4];
    int   t1i[2][4];
    #pragma unroll
    for (int m = 0; m < 2; ++m)
        #pragma unroll
        for (int r = 0; r < 4; ++r) {
            t1v[m][r] = FLT_MAX; t2v[m][r] = FLT_MAX; t1i[m][r] = INT_MAX;
        }

    // one 16KB tile = 64 clusters; ti = global tile index (0..15)
    auto compute = [&](int ti, const char* tileBase) {
        const char* pBb = tileBase + colg * 8192 + lane * 16;
        float w2v[2];
        #pragma unroll
        for (int nt = 0; nt < 2; ++nt)
            w2v[nt] = lw2[ti * 64 + colg * 32 + nt * 16 + laneLo];

        __builtin_amdgcn_s_setprio(1);
        #pragma unroll
        for (int nt = 0; nt < 2; ++nt) {
            f32x4 a0 = (f32x4){0.f, 0.f, 0.f, 0.f};
            f32x4 a1 = (f32x4){0.f, 0.f, 0.f, 0.f};
            #pragma unroll
            for (int k0b = 0; k0b < 4; ++k0b) {
                bf16x8 bh = *reinterpret_cast<const bf16x8*>(pBb + nt * 4096 + k0b * 1024);
                a0 = __builtin_amdgcn_mfma_f32_16x16x32_bf16(ah[0][k0b], bh, a0, 0, 0, 0);
                a1 = __builtin_amdgcn_mfma_f32_16x16x32_bf16(ah[1][k0b], bh, a1, 0, 0, 0);
            }
            // dist = w2 - 2*dot_hi; branch-free top-2 values + top-1 index.
            const int col = ti * 64 + colg * 32 + nt * 16 + laneLo;
            #pragma unroll
            for (int r = 0; r < 4; ++r) {
                float dv0 = fmaf(-2.f, a0[r], w2v[nt]);
                t2v[0][r] = fminf(t2v[0][r], fmaxf(t1v[0][r], dv0));
                t1i[0][r] = (dv0 < t1v[0][r]) ? col : t1i[0][r];
                t1v[0][r] = fminf(t1v[0][r], dv0);
                float dv1 = fmaf(-2.f, a1[r], w2v[nt]);
                t2v[1][r] = fminf(t2v[1][r], fmaxf(t1v[1][r], dv1));
                t1i[1][r] = (dv1 < t1v[1][r]) ? col : t1i[1][r];
                t1v[1][r] = fminf(t1v[1][r], dv1);
            }
        }
        __builtin_amdgcn_s_setprio(0);
    };

    const char* cur = lB0;
    char*       nxt = lB1;
    #pragma unroll 1
    for (int p = 0; p < 8; ++p) {
        if (p < 7) {
            const char* src = (const char*)wh + (size_t)(p + 1) * 32768;
            #pragma unroll
            for (int q = 0; q < 4; ++q)
                gload_lds16(src + wid * 4096 + q * 1024 + lane * 16,
                            nxt + wid * 4096 + q * 1024);
            asm volatile("s_waitcnt vmcnt(4)" ::: "memory");  // phase p landed; p+1 in flight
        } else {
            asm volatile("s_waitcnt vmcnt(0)" ::: "memory");
        }
        __builtin_amdgcn_sched_barrier(0);
        __builtin_amdgcn_s_barrier();                         // everyone's phase p landed
        FENCE();
        compute(2 * p,     cur);
        compute(2 * p + 1, cur + 16384);
        if (p < 7) {
            asm volatile("s_waitcnt lgkmcnt(0)" ::: "memory");
            __builtin_amdgcn_sched_barrier(0);
            __builtin_amdgcn_s_barrier();                     // all waves done reading cur
            FENCE();
            char* tmp = nxt; nxt = (char*)cur; cur = tmp;
        }
    }

    // ---- reduce top-2 across the 16 col-lanes (laneLo) of each row ----
    #pragma unroll
    for (int off = 1; off < 16; off <<= 1) {
        #pragma unroll
        for (int m = 0; m < 2; ++m)
            #pragma unroll
            for (int r = 0; r < 4; ++r) {
                float ov1 = __shfl_xor(t1v[m][r], off, 64);
                int   oi1 = __shfl_xor(t1i[m][r], off, 64);
                float ov2 = __shfl_xor(t2v[m][r], off, 64);
                float nt2 = fminf(fminf(t2v[m][r], ov2), fmaxf(t1v[m][r], ov1));
                if (lexlt(ov1, oi1, t1v[m][r], t1i[m][r])) { t1v[m][r] = ov1; t1i[m][r] = oi1; }
                t2v[m][r] = nt2;
            }
    }

    // ---- merge col-halves via LDS ----
    __syncthreads();
    if (colg == 1 && laneLo == 0) {
        #pragma unroll
        for (int m = 0; m < 2; ++m)
            #pragma unroll
            for (int r = 0; r < 4; ++r) {
                const int row = rowg * 32 + m * 16 + laneHi * 4 + r;
                mscr[row * 4 + 0] = __float_as_int(t1v[m][r]);
                mscr[row * 4 + 1] = t1i[m][r];
                mscr[row * 4 + 2] = __float_as_int(t2v[m][r]);
            }
    }
    __syncthreads();
    double local = 0.0;
    if (colg == 0 && laneLo == 0) {
        #pragma unroll
        for (int m = 0; m < 2; ++m)
            #pragma unroll
            for (int r = 0; r < 4; ++r) {
                const int row = rowg * 32 + m * 16 + laneHi * 4 + r;
                float ov1 = __int_as_float(mscr[row * 4 + 0]);
                int   oi1 = mscr[row * 4 + 1];
                float ov2 = __int_as_float(mscr[row * 4 + 2]);
                float b1v = t1v[m][r], b2v;
                int   b1i = t1i[m][r];
                b2v = fminf(fminf(t2v[m][r], ov2), fmaxf(b1v, ov1));
                if (lexlt(ov1, oi1, b1v, b1i)) { b1v = ov1; b1i = oi1; }
                const int grow = rowbase + row;
                if (b2v - b1v < TAU) {                 // near-tie: exact rescan
                    int slot = atomicAdd(flag_cnt, 1);
                    if (slot < flag_cap) {
                        flag_rows[slot] = grow;
                    } else {
                        cl_out[grow] = (float)b1i;
                        local += (double)(b1v + lx2[row]);
                    }
                } else {
                    cl_out[grow] = (float)b1i;
                    local += (double)(b1v + lx2[row]);
                }
            }
        dred[rowg * 4 + laneHi] = local;
    }
    __syncthreads();
    if (tid == 0) {
        double tt = 0.0;
        for (int i = 0; i < 16; ++i) tt += dred[i];
        atomicAdd(inertia_acc, tt);
    }
}

// refine2: per flagged row, f32 full rescan over all 1024 clusters -> top-2
// candidates -> exact f64 pair decision. 256 threads/block, one row at a time.
__global__ void refine2_kernel(const float* __restrict__ X, const float* __restrict__ W,
                               const float* __restrict__ w2,
                               const int* __restrict__ flag_cnt,
                               const int* __restrict__ flag_rows, int flag_cap,
                               float* __restrict__ cl_out,
                               double* __restrict__ inertia_acc)
{
    __shared__ float xrow[128];
    __shared__ float rv1[4], rv2[4];
    __shared__ int   ri1[4], ri2[4];
    int n = *flag_cnt;
    if (n > flag_cap) n = flag_cap;
    const int tid  = threadIdx.x;
    const int lane = tid & 63;
    const int wv   = tid >> 6;

    for (int f = blockIdx.x; f < n; f += gridDim.x) {
        const int row = flag_rows[f];
        if (tid < 128) xrow[tid] = X[(size_t)row * 128 + tid];
        __syncthreads();

        float v1 = FLT_MAX, v2 = FLT_MAX;
        int   i1 = INT_MAX, i2 = INT_MAX;
        #pragma unroll
        for (int cc = 0; cc < 4; ++cc) {
            const int c = tid + 256 * cc;
            const float* wr = W + (size_t)c * 128;
            float dot = 0.f;
            #pragma unroll 8
            for (int d = 0; d < 128; ++d) dot = fmaf(xrow[d], wr[d], dot);
            float dv = fmaf(-2.f, dot, w2[c]);
            if (lexlt(dv, c, v1, i1)) { v2 = v1; i2 = i1; v1 = dv; i1 = c; }
            else if (lexlt(dv, c, v2, i2)) { v2 = dv; i2 = c; }
        }
        // wave top-2 merge
        #pragma unroll
        for (int off = 1; off < 64; off <<= 1) {
            float ov1 = __shfl_xor(v1, off, 64);
            int   oi1 = __shfl_xor(i1, off, 64);
            float ov2 = __shfl_xor(v2, off, 64);
            int   oi2 = __shfl_xor(i2, off, 64);
            if (lexlt(ov1, oi1, v1, i1)) {
                float nv2; int ni2;
                if (lexlt(v1, i1, ov2, oi2)) { nv2 = v1; ni2 = i1; }
                else                         { nv2 = ov2; ni2 = oi2; }
                v1 = ov1; i1 = oi1; v2 = nv2; i2 = ni2;
            } else if (lexlt(ov1, oi1, v2, i2)) {
                v2 = ov1; i2 = oi1;
            }
        }
        if (lane == 0) { rv1[wv] = v1; ri1[wv] = i1; rv2[wv] = v2; ri2[wv] = i2; }
        __syncthreads();
        if (tid == 0) {
            float b1 = rv1[0], b2 = rv2[0];
            int   c1 = ri1[0], c2 = ri2[0];
            for (int w = 1; w < 4; ++w) {
                float ov1 = rv1[w], ov2 = rv2[w];
                int   oi1 = ri1[w], oi2 = ri2[w];
                if (lexlt(ov1, oi1, b1, c1)) {
                    float nv2; int ni2;
                    if (lexlt(b1, c1, ov2, oi2)) { nv2 = b1; ni2 = c1; }
                    else                         { nv2 = ov2; ni2 = oi2; }
                    b1 = ov1; c1 = oi1; b2 = nv2; c2 = ni2;
                } else if (lexlt(ov1, oi1, b2, c2)) {
                    b2 = ov1; c2 = oi1;
                }
            }
            // exact f64 decision between c1 and c2 (includes x^2)
            const float* wa = W + (size_t)c1 * 128;
            const float* wb = W + (size_t)c2 * 128;
            double d1 = 0.0, d2 = 0.0;
            for (int d = 0; d < 128; ++d) {
                double xv = (double)xrow[d];
                double e1 = xv - (double)wa[d]; d1 = fma(e1, e1, d1);
                double e2 = xv - (double)wb[d]; d2 = fma(e2, e2, d2);
            }
            int win; double dw;
            if (d1 < d2 || (d1 == d2 && c1 < c2)) { win = c1; dw = d1; }
            else                                  { win = c2; dw = d2; }
            cl_out[row] = (float)win;
            atomicAdd(inertia_acc, dw);
        }
        __syncthreads();
    }
}

// ---------------- fallback (3-pass in-kernel conversion, ws too small) ------
__global__ __launch_bounds__(512, 1)
void dist_argmin_v2(const float* __restrict__ X, const float* __restrict__ W,
                    const float* __restrict__ w2g, float* __restrict__ cl_out,
                    double* __restrict__ inertia_acc,
                    int* __restrict__ flag_cnt, int* __restrict__ flag_rows,
                    int flag_cap)
{
    __shared__ __align__(16) char smem[133760];
    short*  Areg = (short*)smem;
    short*  Breg = (short*)(smem + 65536);
    int*    mscr = (int*)(smem + 131072);
    float*  lx2  = (float*)(smem + 131072 + 2048);
    double* dred = (double*)(smem + 131072 + 2048 + 512);

    const int tid    = threadIdx.x;
    const int lane   = tid & 63;
    const int laneLo = lane & 15;
    const int laneHi = lane >> 4;
    const int wid    = tid >> 6;
    const int rowg   = wid >> 1;
    const int colg   = wid & 1;
    const int rowbase = blockIdx.x * 128;

    {
        const int r = tid >> 2, q = tid & 3;
        float s = 0.f;
        #pragma unroll
        for (int j = 0; j < 8; ++j) {
            const int d0 = q * 4 + j * 16;
            float4 v = *reinterpret_cast<const float4*>(X + (size_t)(rowbase + r) * 128 + d0);
            float fv[4] = {v.x, v.y, v.z, v.w};
            s16x4 hv, lv;
            #pragma unroll
            for (int u = 0; u < 4; ++u) {
                s = fmaf(fv[u], fv[u], s);
                short h = f2bf_trunc(fv[u]);
                short l = f2bf_trunc(fv[u] - bf2f(h));
                hv[u] = h; lv[u] = l;
            }
            const int kb = d0 >> 3, off = d0 & 7;
            short* pa = Areg + (kb * 128 + r) * 8 + off;
            *reinterpret_cast<s16x4*>(pa)         = hv;
            *reinterpret_cast<s16x4*>(pa + 16384) = lv;
        }
        s += __shfl_xor(s, 1, 64);
        s += __shfl_xor(s, 2, 64);
        if (q == 0) lx2[r] = s;
    }

    float t1v[2][4], t2v[2][4];
    int   t1i[2][4];
    #pragma unroll
    for (int m = 0; m < 2; ++m)
        #pragma unroll
        for (int r = 0; r < 4; ++r) {
            t1v[m][r] = FLT_MAX; t2v[m][r] = FLT_MAX; t1i[m][r] = INT_MAX;
        }

    const char* pAbase = smem + laneHi * 2048 + (rowg * 32 + laneLo) * 16;
    const char* pBbase = smem + 65536 + colg * 16384 + lane * 16;

    for (int iter = 0; iter < 8; ++iter) {
        __syncthreads();
        {
            const int c = tid >> 2, q = tid & 3;
            const int nt = c >> 4, c15 = c & 15;
            #pragma unroll
            for (int j = 0; j < 8; ++j) {
                const int d0 = q * 4 + j * 16;
                float4 v = *reinterpret_cast<const float4*>(W + (size_t)(iter * 128 + c) * 128 + d0);
                float fv[4] = {v.x, v.y, v.z, v.w};
                s16x4 hv, lv;
                #pragma unroll
                for (int u = 0; u < 4; ++u) {
                    short h = f2bf_trunc(fv[u]);
                    short l = f2bf_trunc(fv[u] - bf2f(h));
                    hv[u] = h; lv[u] = l;
                }
                const int k0b = d0 >> 5, sub = (d0 >> 3) & 3, jj = d0 & 7;
                short* pb = Breg + ((nt * 4 + k0b) * 64 + sub * 16 + c15) * 8 + jj;
                *reinterpret_cast<s16x4*>(pb)         = hv;
                *reinterpret_cast<s16x4*>(pb + 16384) = lv;
            }
        }
        float w2v[4];
        #pragma unroll
        for (int nt = 0; nt < 4; ++nt)
            w2v[nt] = w2g[iter * 128 + colg * 64 + nt * 16 + laneLo];
        __syncthreads();

        f32x4 acc[2][4];
        #pragma unroll
        for (int m = 0; m < 2; ++m)
            #pragma unroll
            for (int nt = 0; nt < 4; ++nt)
                acc[m][nt] = (f32x4){0.f, 0.f, 0.f, 0.f};

        #pragma unroll
        for (int k0b = 0; k0b < 4; ++k0b) {
            bf16x8 ah[2], al[2];
            #pragma unroll
            for (int m = 0; m < 2; ++m) {
                ah[m] = *reinterpret_cast<const bf16x8*>(pAbase + k0b * 8192 + m * 256);
                al[m] = *reinterpret_cast<const bf16x8*>(pAbase + 32768 + k0b * 8192 + m * 256);
            }
            #pragma unroll
            for (int nt = 0; nt < 4; ++nt) {
                bf16x8 bh = *reinterpret_cast<const bf16x8*>(pBbase + nt * 4096 + k0b * 1024);
                bf16x8 bl = *reinterpret_cast<const bf16x8*>(pBbase + 32768 + nt * 4096 + k0b * 1024);
                #pragma unroll
                for (int m = 0; m < 2; ++m) {
                    acc[m][nt] = __builtin_amdgcn_mfma_f32_16x16x32_bf16(ah[m], bh, acc[m][nt], 0, 0, 0);
                    acc[m][nt] = __builtin_amdgcn_mfma_f32_16x16x32_bf16(ah[m], bl, acc[m][nt], 0, 0, 0);
                    acc[m][nt] = __builtin_amdgcn_mfma_f32_16x16x32_bf16(al[m], bh, acc[m][nt], 0, 0, 0);
                }
            }
        }

        #pragma unroll
        for (int nt = 0; nt < 4; ++nt) {
            const int col = iter * 128 + colg * 64 + nt * 16 + laneLo;
            #pragma unroll
            for (int m = 0; m < 2; ++m)
                #pragma unroll
                for (int r = 0; r < 4; ++r) {
                    float dv = fmaf(-2.f, acc[m][nt][r], w2v[nt]);
                    float hi = fmaxf(t1v[m][r], dv);
                    t2v[m][r] = fminf(t2v[m][r], hi);
                    bool cnd = dv < t1v[m][r];
                    t1i[m][r] = cnd ? col : t1i[m][r];
                    t1v[m][r] = fminf(t1v[m][r], dv);
                }
        }
    }

    #pragma unroll
    for (int off = 1; off < 16; off <<= 1) {
        #pragma unroll
        for (int m = 0; m < 2; ++m)
            #pragma unroll
            for (int r = 0; r < 4; ++r) {
                float ov1 = __shfl_xor(t1v[m][r], off, 64);
                int   oi1 = __shfl_xor(t1i[m][r], off, 64);
                float ov2 = __shfl_xor(t2v[m][r], off, 64);
                float nt2 = fminf(fminf(t2v[m][r], ov2), fmaxf(t1v[m][r], ov1));
                if (lexlt(ov1, oi1, t1v[m][r], t1i[m][r])) { t1v[m][r] = ov1; t1i[m][r] = oi1; }
                t2v[m][r] = nt2;
            }
    }

    __syncthreads();
    if (colg == 1 && laneLo == 0) {
        #pragma unroll
        for (int m = 0; m < 2; ++m)
            #pragma unroll
            for (int r = 0; r < 4; ++r) {
                const int row = rowg * 32 + m * 16 + laneHi * 4 + r;
                mscr[row * 4 + 0] = __float_as_int(t1v[m][r]);
                mscr[row * 4 + 1] = t1i[m][r];
                mscr[row * 4 + 2] = __float_as_int(t2v[m][r]);
            }
    }
    __syncthreads();
    double local = 0.0;
    if (colg == 0 && laneLo == 0) {
        #pragma unroll
        for (int m = 0; m < 2; ++m)
            #pragma unroll
            for (int r = 0; r < 4; ++r) {
                const int row = rowg * 32 + m * 16 + laneHi * 4 + r;
                float ov1 = __int_as_float(mscr[row * 4 + 0]);
                int   oi1 = mscr[row * 4 + 1];
                float ov2 = __int_as_float(mscr[row * 4 + 2]);
                float b1v = t1v[m][r], b2v;
                int   b1i = t1i[m][r];
                b2v = fminf(fminf(t2v[m][r], ov2), fmaxf(b1v, ov1));
                if (lexlt(ov1, oi1, b1v, b1i)) { b1v = ov1; b1i = oi1; }
                const int grow = rowbase + row;
                if (b2v - b1v < 1e-3f) {
                    int slot = atomicAdd(flag_cnt, 1);
                    if (slot < flag_cap) flag_rows[slot] = grow;
                    else { cl_out[grow] = (float)b1i; local += (double)(b1v + lx2[row]); }
                } else {
                    cl_out[grow] = (float)b1i;
                    local += (double)(b1v + lx2[row]);
                }
            }
        dred[rowg * 4 + laneHi] = local;
    }
    __syncthreads();
    if (tid == 0) {
        double t = 0.0;
        for (int i = 0; i < 16; ++i) t += dred[i];
        atomicAdd(inertia_acc, t);
    }
}

__global__ void finalize_kernel(const float* __restrict__ W, const float* __restrict__ w2,
                                const double* __restrict__ inertia, float* __restrict__ out)
{
    __shared__ float sh1[128], sh2[128];
    int d = threadIdx.x;                       // 128 threads
    float s = 0.f;
    for (int k = 0; k < 1024; ++k) s += W[(size_t)k * 128 + d];
    float t = 0.f;
    for (int j = 0; j < 8; ++j) t += w2[d + 128 * j];
    sh1[d] = s * s;
    sh2[d] = t;
    __syncthreads();
    for (int off = 64; off > 0; off >>= 1) {
        if (d < off) { sh1[d] += sh1[d + off]; sh2[d] += sh2[d + off]; }
        __syncthreads();
    }
    if (d == 0) {
        float xe = 2.f * sh2[0] - sh1[0];      // 2*trace(G) - sum(G)
        out[1] = xe / 1024.f;
        out[0] = (float)(*inertia / 131072.0);
    }
}

extern "C" void kernel_launch(void* const* d_in, const int* in_sizes, int n_in,
                              void* d_out, int out_size, void* d_ws, size_t ws_size,
                              hipStream_t stream)
{
    const float* X = (const float*)d_in[0];          // [131072,128] f32
    const float* W = (const float*)d_in[1];          // [1024,128]   f32
    float* out = (float*)d_out;                       // [131074]     f32
    char* ws = (char*)d_ws;

    double* inertia  = (double*)ws;
    int*    flag_cnt = (int*)(ws + 8);
    float*  w2       = (float*)(ws + 16);
    short*  wh       = (short*)(ws + 4608);
    int*    flags    = (int*)(ws + 266752);
    const int FCAP = 16384;
    const size_t NEED = 332288;

    const bool precomp = ws_size >= NEED;

    hipMemsetAsync(ws, 0, 16, stream);               // inertia + flag_cnt

    if (precomp) {
        wprep_kernel<<<1024, 128, 0, stream>>>(W, w2, wh, 1);
        dist_argmin_1p<<<1024, 512, 0, stream>>>(X, wh, w2, out + 2, inertia,
                                                 flag_cnt, flags, FCAP);
        refine2_kernel<<<512, 256, 0, stream>>>(X, W, w2, flag_cnt, flags, FCAP,
                                                out + 2, inertia);
    } else {
        int* flagsf = (int*)(ws + 4608);
        long cap = ((long)ws_size - 4608) / 4;
        int capf = cap < 0 ? 0 : (cap > 131072 ? 131072 : (int)cap);
        wprep_kernel<<<1024, 128, 0, stream>>>(W, w2, (short*)flagsf, 0);
        dist_argmin_v2<<<1024, 512, 0, stream>>>(X, W, w2, out + 2, inertia,
                                                 flag_cnt, flagsf, capf);
        refine2_kernel<<<512, 256, 0, stream>>>(X, W, w2, flag_cnt, flagsf, capf,
                                                out + 2, inertia);
    }
    finalize_kernel<<<1, 128, 0, stream>>>(W, w2, inertia, out);
}

// Round 9
// 236.110 us; speedup vs baseline: 2.1883x; 2.1883x over previous
//
#include <hip/hip_runtime.h>
#include <float.h>
#include <limits.h>
#include <math.h>

// ClusterLayer: B=131072 rows, K=1024 clusters, D=128.
// out (float32): [0] inertia/B, [1] xe/K, [2..2+B) cl as float.
//
// R9: 1-pass RNE-fp16 MFMA (11-bit mantissa -> TAU=2.5e-3, ~5x fewer flags
// than bf16), R8's lean tracker + counted-vmcnt sync shape. Flagged rows ->
// wave-per-row refine: f32 full rescan (W read exactly once per row, split-K
// in registers) -> top-2 -> 64-lane-parallel exact f64 pair decision.
//
// ws layout (bytes):
//   0      : double inertia_acc
//   8      : int    flag_cnt
//   16     : float  w2[1024]
//   4608   : short  wh[131072]     (256 KB, fp16-RNE W, tile fragment order)
//   266752 : int    flag_rows[16384]  -> end 332288

#define TAU 2.5e-3f

using f16x8  = __attribute__((ext_vector_type(8))) _Float16;
using bf16x8 = __attribute__((ext_vector_type(8))) short;
using f32x4  = __attribute__((ext_vector_type(4))) float;
using s16x4  = __attribute__((ext_vector_type(4))) short;

static __device__ __forceinline__ short f2bf_trunc(float f) {
    return (short)(__float_as_uint(f) >> 16);
}
static __device__ __forceinline__ float bf2f(short h) {
    return __uint_as_float(((unsigned int)(unsigned short)h) << 16);
}
static __device__ __forceinline__ bool lexlt(float v1, int i1, float v2, int i2) {
    return v1 < v2 || (v1 == v2 && i1 < i2);
}
static __device__ __forceinline__ void gload_lds16(const void* g, void* l) {
    __builtin_amdgcn_global_load_lds(
        (const __attribute__((address_space(1))) unsigned int*)g,
        (__attribute__((address_space(3))) unsigned int*)l, 16, 0, 0);
}
#define FENCE() do { asm volatile("" ::: "memory"); __builtin_amdgcn_sched_barrier(0); } while (0)

// W prep: w2 per cluster (f32-exact) + fp16-RNE image in 64-col-tile fragment
// order: shorts: tile*8192 + (c>>4)*2048 + (d>>5)*512 + ((d>>3)&3)*128
//                + (c&15)*8 + (d&7);   tile=k>>6, c=k&63
__global__ void wprep_kernel(const float* __restrict__ W, float* __restrict__ w2,
                             short* __restrict__ wh, int write_wh)
{
    const int k = blockIdx.x;
    const int d = threadIdx.x;     // 0..127
    float v = W[(size_t)k * 128 + d];
    float sq = v * v;
    for (int off = 1; off < 64; off <<= 1) sq += __shfl_xor(sq, off, 64);
    __shared__ float p[2];
    if ((d & 63) == 0) p[d >> 6] = sq;
    __syncthreads();
    if (d == 0) w2[k] = p[0] + p[1];
    if (write_wh) {
        _Float16 h = (_Float16)v;                       // RNE
        const int tile = k >> 6, c = k & 63;
        size_t base = (size_t)tile * 8192 + (size_t)(c >> 4) * 2048 + (size_t)(d >> 5) * 512
                    + (size_t)((d >> 3) & 3) * 128 + (size_t)(c & 15) * 8 + (size_t)(d & 7);
        wh[base] = *reinterpret_cast<short*>(&h);
    }
}

// LDS (bytes): lB0 0..32768 | lB1 32768..65536 | lw2 65536..69632 |
//              lx2 69632..70144 | mscr 70144..72192 (128 x 4 ints) |
//              dred 72192..72320
__global__ __launch_bounds__(512, 4)
void dist_argmin_1p(const float* __restrict__ X, const short* __restrict__ wh,
                    const float* __restrict__ w2g, float* __restrict__ cl_out,
                    double* __restrict__ inertia_acc,
                    int* __restrict__ flag_cnt, int* __restrict__ flag_rows,
                    int flag_cap)
{
    __shared__ __align__(16) char smem[72320];
    char*   lB0  = smem;
    char*   lB1  = smem + 32768;
    float*  lw2  = (float*)(smem + 65536);
    float*  lx2  = (float*)(smem + 69632);
    int*    mscr = (int*)(smem + 70144);
    double* dred = (double*)(smem + 72192);

    const int tid    = threadIdx.x;
    const int lane   = tid & 63;
    const int laneLo = lane & 15;
    const int laneHi = lane >> 4;
    const int wid    = tid >> 6;
    const int rowg   = wid >> 1;
    const int colg   = wid & 1;
    const int rowbase = blockIdx.x * 128;

    // w2 -> LDS (K-loop must have zero global loads so vmcnt counting holds)
    lw2[tid]       = w2g[tid];
    lw2[tid + 512] = w2g[tid + 512];

    // ---- A (fp16 RNE) straight from global into registers + ||x||^2 ----
    f16x8 ah[2][4];
    #pragma unroll
    for (int m = 0; m < 2; ++m) {
        const float* xp = X + (size_t)(rowbase + rowg * 32 + m * 16 + laneLo) * 128 + laneHi * 8;
        float s = 0.f;
        #pragma unroll
        for (int k0b = 0; k0b < 4; ++k0b) {
            float4 v0 = *reinterpret_cast<const float4*>(xp + k0b * 32);
            float4 v1 = *reinterpret_cast<const float4*>(xp + k0b * 32 + 4);
            float fv[8] = {v0.x, v0.y, v0.z, v0.w, v1.x, v1.y, v1.z, v1.w};
            f16x8 hv;
            #pragma unroll
            for (int u = 0; u < 8; ++u) {
                s = fmaf(fv[u], fv[u], s);
                hv[u] = (_Float16)fv[u];               // RNE
            }
            ah[m][k0b] = hv;
        }
        s += __shfl_xor(s, 16, 64);     // combine 4 laneHi dim-slices
        s += __shfl_xor(s, 32, 64);
        if (colg == 0 && laneHi == 0) lx2[rowg * 32 + m * 16 + laneLo] = s;
    }

    // ---- issue phase 0 DMA -> lB0 (32 KB = 128 clusters; 4 x 16B/thread) ----
    #pragma unroll
    for (int q = 0; q < 4; ++q)
        gload_lds16((const char*)wh + wid * 4096 + q * 1024 + lane * 16,
                    lB0 + wid * 4096 + q * 1024);

    // drain my lw2/lx2 ds_writes before the first in-loop barrier
    asm volatile("s_waitcnt lgkmcnt(0)" ::: "memory");
    __builtin_amdgcn_sched_barrier(0);

    float t1v[2][4], t2v[2][4];
    int   t1i[2][4];
    #pragma unroll
    for (int m = 0; m < 2; ++m)
        #pragma unroll
        for (int r = 0; r < 4; ++r) {
            t1v[m][r] = FLT_MAX; t2v[m][r] = FLT_MAX; t1i[m][r] = INT_MAX;
        }

    // one 16KB tile = 64 clusters; ti = global tile index (0..15)
    auto compute = [&](int ti, const char* tileBase) {
        const char* pBb = tileBase + colg * 8192 + lane * 16;
        float w2v[2];
        #pragma unroll
        for (int nt = 0; nt < 2; ++nt)
            w2v[nt] = lw2[ti * 64 + colg * 32 + nt * 16 + laneLo];

        __builtin_amdgcn_s_setprio(1);
        #pragma unroll
        for (int nt = 0; nt < 2; ++nt) {
            f32x4 a0 = (f32x4){0.f, 0.f, 0.f, 0.f};
            f32x4 a1 = (f32x4){0.f, 0.f, 0.f, 0.f};
            #pragma unroll
            for (int k0b = 0; k0b < 4; ++k0b) {
                f16x8 bh = *reinterpret_cast<const f16x8*>(pBb + nt * 4096 + k0b * 1024);
                a0 = __builtin_amdgcn_mfma_f32_16x16x32_f16(ah[0][k0b], bh, a0, 0, 0, 0);
                a1 = __builtin_amdgcn_mfma_f32_16x16x32_f16(ah[1][k0b], bh, a1, 0, 0, 0);
            }
            // dist = w2 - 2*dot_f16; branch-free top-2 values + top-1 index.
            const int col = ti * 64 + colg * 32 + nt * 16 + laneLo;
            #pragma unroll
            for (int r = 0; r < 4; ++r) {
                float dv0 = fmaf(-2.f, a0[r], w2v[nt]);
                t2v[0][r] = fminf(t2v[0][r], fmaxf(t1v[0][r], dv0));
                t1i[0][r] = (dv0 < t1v[0][r]) ? col : t1i[0][r];
                t1v[0][r] = fminf(t1v[0][r], dv0);
                float dv1 = fmaf(-2.f, a1[r], w2v[nt]);
                t2v[1][r] = fminf(t2v[1][r], fmaxf(t1v[1][r], dv1));
                t1i[1][r] = (dv1 < t1v[1][r]) ? col : t1i[1][r];
                t1v[1][r] = fminf(t1v[1][r], dv1);
            }
        }
        __builtin_amdgcn_s_setprio(0);
    };

    const char* cur = lB0;
    char*       nxt = lB1;
    #pragma unroll 1
    for (int p = 0; p < 8; ++p) {
        if (p < 7) {
            const char* src = (const char*)wh + (size_t)(p + 1) * 32768;
            #pragma unroll
            for (int q = 0; q < 4; ++q)
                gload_lds16(src + wid * 4096 + q * 1024 + lane * 16,
                            nxt + wid * 4096 + q * 1024);
            asm volatile("s_waitcnt vmcnt(4)" ::: "memory");  // phase p landed; p+1 in flight
        } else {
            asm volatile("s_waitcnt vmcnt(0)" ::: "memory");
        }
        __builtin_amdgcn_sched_barrier(0);
        __builtin_amdgcn_s_barrier();                         // everyone's phase p landed
        FENCE();
        compute(2 * p,     cur);
        compute(2 * p + 1, cur + 16384);
        if (p < 7) {
            asm volatile("s_waitcnt lgkmcnt(0)" ::: "memory");
            __builtin_amdgcn_sched_barrier(0);
            __builtin_amdgcn_s_barrier();                     // all waves done reading cur
            FENCE();
            char* tmp = nxt; nxt = (char*)cur; cur = tmp;
        }
    }

    // ---- reduce top-2 across the 16 col-lanes (laneLo) of each row ----
    #pragma unroll
    for (int off = 1; off < 16; off <<= 1) {
        #pragma unroll
        for (int m = 0; m < 2; ++m)
            #pragma unroll
            for (int r = 0; r < 4; ++r) {
                float ov1 = __shfl_xor(t1v[m][r], off, 64);
                int   oi1 = __shfl_xor(t1i[m][r], off, 64);
                float ov2 = __shfl_xor(t2v[m][r], off, 64);
                float nt2 = fminf(fminf(t2v[m][r], ov2), fmaxf(t1v[m][r], ov1));
                if (lexlt(ov1, oi1, t1v[m][r], t1i[m][r])) { t1v[m][r] = ov1; t1i[m][r] = oi1; }
                t2v[m][r] = nt2;
            }
    }

    // ---- merge col-halves via LDS ----
    __syncthreads();
    if (colg == 1 && laneLo == 0) {
        #pragma unroll
        for (int m = 0; m < 2; ++m)
            #pragma unroll
            for (int r = 0; r < 4; ++r) {
                const int row = rowg * 32 + m * 16 + laneHi * 4 + r;
                mscr[row * 4 + 0] = __float_as_int(t1v[m][r]);
                mscr[row * 4 + 1] = t1i[m][r];
                mscr[row * 4 + 2] = __float_as_int(t2v[m][r]);
            }
    }
    __syncthreads();
    double local = 0.0;
    if (colg == 0 && laneLo == 0) {
        #pragma unroll
        for (int m = 0; m < 2; ++m)
            #pragma unroll
            for (int r = 0; r < 4; ++r) {
                const int row = rowg * 32 + m * 16 + laneHi * 4 + r;
                float ov1 = __int_as_float(mscr[row * 4 + 0]);
                int   oi1 = mscr[row * 4 + 1];
                float ov2 = __int_as_float(mscr[row * 4 + 2]);
                float b1v = t1v[m][r], b2v;
                int   b1i = t1i[m][r];
                b2v = fminf(fminf(t2v[m][r], ov2), fmaxf(b1v, ov1));
                if (lexlt(ov1, oi1, b1v, b1i)) { b1v = ov1; b1i = oi1; }
                const int grow = rowbase + row;
                if (b2v - b1v < TAU) {                 // near-tie: exact rescan
                    int slot = atomicAdd(flag_cnt, 1);
                    if (slot < flag_cap) {
                        flag_rows[slot] = grow;
                    } else {
                        cl_out[grow] = (float)b1i;
                        local += (double)(b1v + lx2[row]);
                    }
                } else {
                    cl_out[grow] = (float)b1i;
                    local += (double)(b1v + lx2[row]);
                }
            }
        dred[rowg * 4 + laneHi] = local;
    }
    __syncthreads();
    if (tid == 0) {
        double tt = 0.0;
        for (int i = 0; i < 16; ++i) tt += dred[i];
        atomicAdd(inertia_acc, tt);
    }
}

// refine: one WAVE per flagged row. lane=(kpart,cgrp): kpart=lane>>3 owns dims
// kpart*16..+16 (in registers), cgrp=lane&7 owns clusters cgrp*128..+128.
// Each W element is read exactly once per row (float4). f32 rescan -> top-2
// (lexicographic) -> 64-lane-parallel exact f64 pair decision.
__global__ __launch_bounds__(256)
void refine_kernel(const float* __restrict__ X, const float* __restrict__ W,
                   const float* __restrict__ w2,
                   const int* __restrict__ flag_cnt,
                   const int* __restrict__ flag_rows, int flag_cap,
                   float* __restrict__ cl_out, double* __restrict__ inertia_acc)
{
    int n = *flag_cnt;
    if (n > flag_cap) n = flag_cap;
    const int lane  = threadIdx.x & 63;
    const int wv    = threadIdx.x >> 6;
    const int kpart = lane >> 3;      // 0..7
    const int cgrp  = lane & 7;       // 0..7

    for (int f = blockIdx.x * 4 + wv; f < n; f += gridDim.x * 4) {
        const int row = flag_rows[f];
        const float* xr = X + (size_t)row * 128;
        const float* xk = xr + kpart * 16;
        float4 xa = *reinterpret_cast<const float4*>(xk);
        float4 xb = *reinterpret_cast<const float4*>(xk + 4);
        float4 xc = *reinterpret_cast<const float4*>(xk + 8);
        float4 xd = *reinterpret_cast<const float4*>(xk + 12);

        float v1 = FLT_MAX, v2 = FLT_MAX;
        int   i1 = INT_MAX, i2 = INT_MAX;
        #pragma unroll 4
        for (int q = 0; q < 128; ++q) {
            const int c = cgrp * 128 + q;
            const float* wr = W + (size_t)c * 128 + kpart * 16;
            float4 wa = *reinterpret_cast<const float4*>(wr);
            float4 wb = *reinterpret_cast<const float4*>(wr + 4);
            float4 wc = *reinterpret_cast<const float4*>(wr + 8);
            float4 wd = *reinterpret_cast<const float4*>(wr + 12);
            float p0 = fmaf(xa.w, wa.w, fmaf(xa.z, wa.z, fmaf(xa.y, wa.y, xa.x * wa.x)));
            float p1 = fmaf(xb.w, wb.w, fmaf(xb.z, wb.z, fmaf(xb.y, wb.y, xb.x * wb.x)));
            float p2 = fmaf(xc.w, wc.w, fmaf(xc.z, wc.z, fmaf(xc.y, wc.y, xc.x * wc.x)));
            float p3 = fmaf(xd.w, wd.w, fmaf(xd.z, wd.z, fmaf(xd.y, wd.y, xd.x * wd.x)));
            float p = (p0 + p1) + (p2 + p3);
            p += __shfl_xor(p, 8, 64);          // reduce over kpart
            p += __shfl_xor(p, 16, 64);
            p += __shfl_xor(p, 32, 64);
            float dv = fmaf(-2.f, p, w2[c]);
            if (dv < v1) { v2 = v1; i2 = i1; v1 = dv; i1 = c; }   // c ascending
            else if (dv < v2) { v2 = dv; i2 = c; }
        }
        // merge top-2 across the 8 cgrps (xor 1,2,4)
        #pragma unroll
        for (int off = 1; off < 8; off <<= 1) {
            float ov1 = __shfl_xor(v1, off, 64);
            int   oi1 = __shfl_xor(i1, off, 64);
            float ov2 = __shfl_xor(v2, off, 64);
            int   oi2 = __shfl_xor(i2, off, 64);
            if (lexlt(ov1, oi1, v1, i1)) {
                float nv2; int ni2;
                if (lexlt(v1, i1, ov2, oi2)) { nv2 = v1; ni2 = i1; }
                else                         { nv2 = ov2; ni2 = oi2; }
                v1 = ov1; i1 = oi1; v2 = nv2; i2 = ni2;
            } else if (lexlt(ov1, oi1, v2, i2)) {
                v2 = ov1; i2 = oi1;
            }
        }
        // exact f64 pair decision, parallel over 64 lanes (2 dims each)
        const float* wa = W + (size_t)i1 * 128;
        const float* wb = W + (size_t)i2 * 128;
        double d1 = 0.0, d2 = 0.0;
        #pragma unroll
        for (int j = 0; j < 2; ++j) {
            const int d = lane * 2 + j;
            double xv = (double)xr[d];
            double e1 = xv - (double)wa[d]; d1 = fma(e1, e1, d1);
            double e2 = xv - (double)wb[d]; d2 = fma(e2, e2, d2);
        }
        #pragma unroll
        for (int off = 1; off < 64; off <<= 1) {
            d1 += __shfl_xor(d1, off, 64);
            d2 += __shfl_xor(d2, off, 64);
        }
        if (lane == 0) {
            int win; double dw;
            if (d1 < d2 || (d1 == d2 && i1 < i2)) { win = i1; dw = d1; }
            else                                  { win = i2; dw = d2; }
            cl_out[row] = (float)win;
            atomicAdd(inertia_acc, dw);
        }
    }
}

// ---------------- fallback (3-pass bf16 in-kernel conversion, ws too small) --
__global__ __launch_bounds__(512, 1)
void dist_argmin_v2(const float* __restrict__ X, const float* __restrict__ W,
                    const float* __restrict__ w2g, float* __restrict__ cl_out,
                    double* __restrict__ inertia_acc,
                    int* __restrict__ flag_cnt, int* __restrict__ flag_rows,
                    int flag_cap)
{
    __shared__ __align__(16) char smem[133760];
    short*  Areg = (short*)smem;
    short*  Breg = (short*)(smem + 65536);
    int*    mscr = (int*)(smem + 131072);
    float*  lx2  = (float*)(smem + 131072 + 2048);
    double* dred = (double*)(smem + 131072 + 2048 + 512);

    const int tid    = threadIdx.x;
    const int lane   = tid & 63;
    const int laneLo = lane & 15;
    const int laneHi = lane >> 4;
    const int wid    = tid >> 6;
    const int rowg   = wid >> 1;
    const int colg   = wid & 1;
    const int rowbase = blockIdx.x * 128;

    {
        const int r = tid >> 2, q = tid & 3;
        float s = 0.f;
        #pragma unroll
        for (int j = 0; j < 8; ++j) {
            const int d0 = q * 4 + j * 16;
            float4 v = *reinterpret_cast<const float4*>(X + (size_t)(rowbase + r) * 128 + d0);
            float fv[4] = {v.x, v.y, v.z, v.w};
            s16x4 hv, lv;
            #pragma unroll
            for (int u = 0; u < 4; ++u) {
                s = fmaf(fv[u], fv[u], s);
                short h = f2bf_trunc(fv[u]);
                short l = f2bf_trunc(fv[u] - bf2f(h));
                hv[u] = h; lv[u] = l;
            }
            const int kb = d0 >> 3, off = d0 & 7;
            short* pa = Areg + (kb * 128 + r) * 8 + off;
            *reinterpret_cast<s16x4*>(pa)         = hv;
            *reinterpret_cast<s16x4*>(pa + 16384) = lv;
        }
        s += __shfl_xor(s, 1, 64);
        s += __shfl_xor(s, 2, 64);
        if (q == 0) lx2[r] = s;
    }

    float t1v[2][4], t2v[2][4];
    int   t1i[2][4];
    #pragma unroll
    for (int m = 0; m < 2; ++m)
        #pragma unroll
        for (int r = 0; r < 4; ++r) {
            t1v[m][r] = FLT_MAX; t2v[m][r] = FLT_MAX; t1i[m][r] = INT_MAX;
        }

    const char* pAbase = smem + laneHi * 2048 + (rowg * 32 + laneLo) * 16;
    const char* pBbase = smem + 65536 + colg * 16384 + lane * 16;

    for (int iter = 0; iter < 8; ++iter) {
        __syncthreads();
        {
            const int c = tid >> 2, q = tid & 3;
            const int nt = c >> 4, c15 = c & 15;
            #pragma unroll
            for (int j = 0; j < 8; ++j) {
                const int d0 = q * 4 + j * 16;
                float4 v = *reinterpret_cast<const float4*>(W + (size_t)(iter * 128 + c) * 128 + d0);
                float fv[4] = {v.x, v.y, v.z, v.w};
                s16x4 hv, lv;
                #pragma unroll
                for (int u = 0; u < 4; ++u) {
                    short h = f2bf_trunc(fv[u]);
                    short l = f2bf_trunc(fv[u] - bf2f(h));
                    hv[u] = h; lv[u] = l;
                }
                const int k0b = d0 >> 5, sub = (d0 >> 3) & 3, jj = d0 & 7;
                short* pb = Breg + ((nt * 4 + k0b) * 64 + sub * 16 + c15) * 8 + jj;
                *reinterpret_cast<s16x4*>(pb)         = hv;
                *reinterpret_cast<s16x4*>(pb + 16384) = lv;
            }
        }
        float w2v[4];
        #pragma unroll
        for (int nt = 0; nt < 4; ++nt)
            w2v[nt] = w2g[iter * 128 + colg * 64 + nt * 16 + laneLo];
        __syncthreads();

        f32x4 acc[2][4];
        #pragma unroll
        for (int m = 0; m < 2; ++m)
            #pragma unroll
            for (int nt = 0; nt < 4; ++nt)
                acc[m][nt] = (f32x4){0.f, 0.f, 0.f, 0.f};

        #pragma unroll
        for (int k0b = 0; k0b < 4; ++k0b) {
            bf16x8 ah[2], al[2];
            #pragma unroll
            for (int m = 0; m < 2; ++m) {
                ah[m] = *reinterpret_cast<const bf16x8*>(pAbase + k0b * 8192 + m * 256);
                al[m] = *reinterpret_cast<const bf16x8*>(pAbase + 32768 + k0b * 8192 + m * 256);
            }
            #pragma unroll
            for (int nt = 0; nt < 4; ++nt) {
                bf16x8 bh = *reinterpret_cast<const bf16x8*>(pBbase + nt * 4096 + k0b * 1024);
                bf16x8 bl = *reinterpret_cast<const bf16x8*>(pBbase + 32768 + nt * 4096 + k0b * 1024);
                #pragma unroll
                for (int m = 0; m < 2; ++m) {
                    acc[m][nt] = __builtin_amdgcn_mfma_f32_16x16x32_bf16(ah[m], bh, acc[m][nt], 0, 0, 0);
                    acc[m][nt] = __builtin_amdgcn_mfma_f32_16x16x32_bf16(ah[m], bl, acc[m][nt], 0, 0, 0);
                    acc[m][nt] = __builtin_amdgcn_mfma_f32_16x16x32_bf16(al[m], bh, acc[m][nt], 0, 0, 0);
                }
            }
        }

        #pragma unroll
        for (int nt = 0; nt < 4; ++nt) {
            const int col = iter * 128 + colg * 64 + nt * 16 + laneLo;
            #pragma unroll
            for (int m = 0; m < 2; ++m)
                #pragma unroll
                for (int r = 0; r < 4; ++r) {
                    float dv = fmaf(-2.f, acc[m][nt][r], w2v[nt]);
                    float hi = fmaxf(t1v[m][r], dv);
                    t2v[m][r] = fminf(t2v[m][r], hi);
                    bool cnd = dv < t1v[m][r];
                    t1i[m][r] = cnd ? col : t1i[m][r];
                    t1v[m][r] = fminf(t1v[m][r], dv);
                }
        }
    }

    #pragma unroll
    for (int off = 1; off < 16; off <<= 1) {
        #pragma unroll
        for (int m = 0; m < 2; ++m)
            #pragma unroll
            for (int r = 0; r < 4; ++r) {
                float ov1 = __shfl_xor(t1v[m][r], off, 64);
                int   oi1 = __shfl_xor(t1i[m][r], off, 64);
                float ov2 = __shfl_xor(t2v[m][r], off, 64);
                float nt2 = fminf(fminf(t2v[m][r], ov2), fmaxf(t1v[m][r], ov1));
                if (lexlt(ov1, oi1, t1v[m][r], t1i[m][r])) { t1v[m][r] = ov1; t1i[m][r] = oi1; }
                t2v[m][r] = nt2;
            }
    }

    __syncthreads();
    if (colg == 1 && laneLo == 0) {
        #pragma unroll
        for (int m = 0; m < 2; ++m)
            #pragma unroll
            for (int r = 0; r < 4; ++r) {
                const int row = rowg * 32 + m * 16 + laneHi * 4 + r;
                mscr[row * 4 + 0] = __float_as_int(t1v[m][r]);
                mscr[row * 4 + 1] = t1i[m][r];
                mscr[row * 4 + 2] = __float_as_int(t2v[m][r]);
            }
    }
    __syncthreads();
    double local = 0.0;
    if (colg == 0 && laneLo == 0) {
        #pragma unroll
        for (int m = 0; m < 2; ++m)
            #pragma unroll
            for (int r = 0; r < 4; ++r) {
                const int row = rowg * 32 + m * 16 + laneHi * 4 + r;
                float ov1 = __int_as_float(mscr[row * 4 + 0]);
                int   oi1 = mscr[row * 4 + 1];
                float ov2 = __int_as_float(mscr[row * 4 + 2]);
                float b1v = t1v[m][r], b2v;
                int   b1i = t1i[m][r];
                b2v = fminf(fminf(t2v[m][r], ov2), fmaxf(b1v, ov1));
                if (lexlt(ov1, oi1, b1v, b1i)) { b1v = ov1; b1i = oi1; }
                const int grow = rowbase + row;
                if (b2v - b1v < 1e-3f) {
                    int slot = atomicAdd(flag_cnt, 1);
                    if (slot < flag_cap) flag_rows[slot] = grow;
                    else { cl_out[grow] = (float)b1i; local += (double)(b1v + lx2[row]); }
                } else {
                    cl_out[grow] = (float)b1i;
                    local += (double)(b1v + lx2[row]);
                }
            }
        dred[rowg * 4 + laneHi] = local;
    }
    __syncthreads();
    if (tid == 0) {
        double t = 0.0;
        for (int i = 0; i < 16; ++i) t += dred[i];
        atomicAdd(inertia_acc, t);
    }
}

__global__ void finalize_kernel(const float* __restrict__ W, const float* __restrict__ w2,
                                const double* __restrict__ inertia, float* __restrict__ out)
{
    __shared__ float sh1[128], sh2[128];
    int d = threadIdx.x;                       // 128 threads
    float s = 0.f;
    for (int k = 0; k < 1024; ++k) s += W[(size_t)k * 128 + d];
    float t = 0.f;
    for (int j = 0; j < 8; ++j) t += w2[d + 128 * j];
    sh1[d] = s * s;
    sh2[d] = t;
    __syncthreads();
    for (int off = 64; off > 0; off >>= 1) {
        if (d < off) { sh1[d] += sh1[d + off]; sh2[d] += sh2[d + off]; }
        __syncthreads();
    }
    if (d == 0) {
        float xe = 2.f * sh2[0] - sh1[0];      // 2*trace(G) - sum(G)
        out[1] = xe / 1024.f;
        out[0] = (float)(*inertia / 131072.0);
    }
}

extern "C" void kernel_launch(void* const* d_in, const int* in_sizes, int n_in,
                              void* d_out, int out_size, void* d_ws, size_t ws_size,
                              hipStream_t stream)
{
    const float* X = (const float*)d_in[0];          // [131072,128] f32
    const float* W = (const float*)d_in[1];          // [1024,128]   f32
    float* out = (float*)d_out;                       // [131074]     f32
    char* ws = (char*)d_ws;

    double* inertia  = (double*)ws;
    int*    flag_cnt = (int*)(ws + 8);
    float*  w2       = (float*)(ws + 16);
    short*  wh       = (short*)(ws + 4608);
    int*    flags    = (int*)(ws + 266752);
    const int FCAP = 16384;
    const size_t NEED = 332288;

    const bool precomp = ws_size >= NEED;

    hipMemsetAsync(ws, 0, 16, stream);               // inertia + flag_cnt

    if (precomp) {
        wprep_kernel<<<1024, 128, 0, stream>>>(W, w2, wh, 1);
        dist_argmin_1p<<<1024, 512, 0, stream>>>(X, wh, w2, out + 2, inertia,
                                                 flag_cnt, flags, FCAP);
        refine_kernel<<<512, 256, 0, stream>>>(X, W, w2, flag_cnt, flags, FCAP,
                                               out + 2, inertia);
    } else {
        int* flagsf = (int*)(ws + 4608);
        long cap = ((long)ws_size - 4608) / 4;
        int capf = cap < 0 ? 0 : (cap > 131072 ? 131072 : (int)cap);
        wprep_kernel<<<1024, 128, 0, stream>>>(W, w2, (short*)flagsf, 0);
        dist_argmin_v2<<<1024, 512, 0, stream>>>(X, W, w2, out + 2, inertia,
                                                 flag_cnt, flagsf, capf);
        refine_kernel<<<512, 256, 0, stream>>>(X, W, w2, flag_cnt, flagsf, capf,
                                               out + 2, inertia);
    }
    finalize_kernel<<<1, 128, 0, stream>>>(W, w2, inertia, out);
}